// Round 6
// baseline (204.919 us; speedup 1.0000x reference)
//
#include <hip/hip_runtime.h>
#include <hip/hip_bf16.h>

#define NS 32768          // B*S samples
#define EMB 512
#define KDIM 2048

typedef float f32x16 __attribute__((ext_vector_type(16)));
typedef __bf16 bf16x8 __attribute__((ext_vector_type(8)));
typedef __bf16 bf16x4 __attribute__((ext_vector_type(4)));
typedef unsigned int u32;
typedef const __attribute__((address_space(1))) u32* gptr_t;
typedef __attribute__((address_space(3))) u32* lptr_t;

__device__ __forceinline__ void gload_lds16(const void* g, void* l) {
    __builtin_amdgcn_global_load_lds((gptr_t)g, (lptr_t)l, 16, 0, 0);
}

// ---- prep: W2 -> bf16 (1024 blocks); block 1024: W1 -> bf16 [2048][8], b1 -> bf16 ----
__global__ __launch_bounds__(256) void k_prep(const float* __restrict__ W2,
                                              const float* __restrict__ W1,
                                              const float* __restrict__ b1,
                                              __hip_bfloat16* __restrict__ W2b,
                                              __hip_bfloat16* __restrict__ W1b,
                                              __hip_bfloat16* __restrict__ b1b) {
    int t = threadIdx.x;
    if (blockIdx.x < 1024) {
        int i = (blockIdx.x * 256 + t) * 4;
        float4 v = *(const float4*)(W2 + i);
        __hip_bfloat16 o[4];
        o[0] = __float2bfloat16(v.x); o[1] = __float2bfloat16(v.y);
        o[2] = __float2bfloat16(v.z); o[3] = __float2bfloat16(v.w);
        *(ulong1*)(W2b + i) = *(ulong1*)o;
    } else {
        __hip_bfloat16 bb[8];
        #pragma unroll
        for (int r = 0; r < 8; r++) {
            int row = t * 8 + r;
            float4 a = *(const float4*)(W1 + (size_t)row * 8);
            float4 b = *(const float4*)(W1 + (size_t)row * 8 + 4);
            __hip_bfloat16 p[8];
            p[0] = __float2bfloat16(a.x); p[1] = __float2bfloat16(a.y);
            p[2] = __float2bfloat16(a.z); p[3] = __float2bfloat16(a.w);
            p[4] = __float2bfloat16(b.x); p[5] = __float2bfloat16(b.y);
            p[6] = __float2bfloat16(b.z); p[7] = __float2bfloat16(b.w);
            *(bf16x8*)(W1b + (size_t)row * 8) = *(bf16x8*)p;
            bb[r] = __float2bfloat16(b1[row]);
        }
        *(bf16x8*)(b1b + t * 8) = *(bf16x8*)bb;
    }
}

// ---- fused: C = relu(ev @ W1^T + b1) @ W2b^T + b2 ----
// Per iter (K-window of 32):
//   h-MFMA: hT[kc][s] = sum_w W1aug[kc][w] * evaug[s][w]  (bias on virtual wire 8)
//   -> relu/cvt -> hs (LDS) in A-fragment order -> lgkm-only barrier ->
//   16 main MFMAs; B-fragments loaded global->VGPR (L2-resident W2b),
//   loads stay in flight across the barrier (no vmcnt drain).
#define BM 128
#define BN 256

__global__ __launch_bounds__(256, 2) void k_gemm(
        const float* __restrict__ x,       // [NS, 8]
        const float* __restrict__ params,  // [8, 3]
        const __hip_bfloat16* __restrict__ W1b,  // [2048, 8] bf16
        const __hip_bfloat16* __restrict__ b1b,  // [2048] bf16
        const __hip_bfloat16* __restrict__ W2b,  // [512, 2048] bf16
        const float* __restrict__ b2,      // [512]
        float* __restrict__ C) {           // [NS, 512]
    __shared__ __hip_bfloat16 W1s[KDIM * 8];   // 32 KB
    __shared__ __hip_bfloat16 b1s[KDIM];       // 4 KB
    __shared__ __hip_bfloat16 hs[2][8][512];   // 16 KB: [buf][slab(t*4+mtile)][bytes/2]

    int tid = threadIdx.x, wave = tid >> 6, lane = tid & 63;
    int l31 = lane & 31, hh = lane >> 5;
    int wr = wave >> 1, wc = wave & 1;
    int bx = blockIdx.x, bm = bx >> 1, bn = bx & 1;

    // one-time: stage W1 (32 KB) + b1 (4 KB) into LDS, linear copy
    #pragma unroll
    for (int r = 0; r < 8; r++)
        gload_lds16(W1b + (size_t)(r * 256 + tid) * 8, &W1s[(r * 256 + tid) * 8]);
    gload_lds16(b1b + tid * 8, &b1s[tid * 8]);

    // --- inline ev for this thread's sample row (both halves compute same row)
    int row = bm * BM + wave * 32 + l31;
    float evv[8];
    {
        float K1[8], K2[8];
        #pragma unroll
        for (int i = 0; i < 8; i++) {
            float a = params[i*3+0], b = params[i*3+1], g = params[i*3+2];
            float sa, ca, sb, cb, sg, cg;
            __sincosf(a, &sa, &ca);
            __sincosf(b, &sb, &cb);
            __sincosf(g, &sg, &cg);
            K1[i] = sa*sb*sg + ca*cg;
            K2[i] = cb*sg;
        }
        float4 x0 = *(const float4*)(x + (size_t)row * 8);
        float4 x1 = *(const float4*)(x + (size_t)row * 8 + 4);
        float xs[8] = {x0.x, x0.y, x0.z, x0.w, x1.x, x1.y, x1.z, x1.w};
        float z[8];
        #pragma unroll
        for (int i = 0; i < 8; i++) {
            float s, c;
            __sincosf(xs[i], &s, &c);
            z[i] = c * K1[i] - s * K2[i];
        }
        float p = z[0];
        #pragma unroll
        for (int j = 1; j < 8; j++) { p *= z[j]; evv[j] = p; }
        float sfx = z[7];
        #pragma unroll
        for (int j = 6; j >= 1; j--) sfx *= z[j];
        evv[0] = sfx;
    }
    // B-operand of h-MFMA: h half 0 = ev wires; half 1 = {1,0,...} (bias wire)
    bf16x8 evB;
    #pragma unroll
    for (int i = 0; i < 8; i++)
        evB[i] = hh ? (__bf16)(i == 0 ? 1.f : 0.f) : (__bf16)evv[i];

    __syncthreads();   // W1s/b1s staged (drains gload_lds vmcnt too)

    // B-fragment base: frag (ni,t): rows bn*BN + wc*128 + ni*32 + l31, k-half hh
    const __hip_bfloat16* Bbase = W2b + (size_t)(bn*BN + wc*128 + l31) * KDIM + hh * 8;

    f32x16 acc[2][4] = {};   // [mi][ni]

    #pragma unroll 2
    for (int k0 = 0; k0 < KDIM; k0 += 32) {
        int cb = (k0 >> 5) & 1;
        // B loads for this iter (global->VGPR, overlap with h-gen below)
        bf16x8 Bf[8];
        #pragma unroll
        for (int ni = 0; ni < 4; ni++)
            #pragma unroll
            for (int t = 0; t < 2; t++)
                Bf[ni*2+t] = *(const bf16x8*)(Bbase + (size_t)ni*32*KDIM + k0 + t*16);

        // h-gen: A-op = W1 row (half 0) / bias row (half 1)
        bf16x8 w8 = *(const bf16x8*)&W1s[(k0 + l31) * 8];
        __bf16 bias1 = ((const __bf16*)b1s)[k0 + l31];
        bf16x8 aop;
        #pragma unroll
        for (int i = 0; i < 8; i++)
            aop[i] = hh ? (i == 0 ? bias1 : (__bf16)0.f) : w8[i];
        f32x16 ha = __builtin_amdgcn_mfma_f32_32x32x16_bf16(aop, evB, (f32x16){0}, 0, 0, 0);

        // relu + cvt + write hs in A-frag order: value r -> kc_off = 4hh+(r&3)+8(r>>2)
        #pragma unroll
        for (int g = 0; g < 4; g++) {
            bf16x4 hv;
            #pragma unroll
            for (int i = 0; i < 4; i++) hv[i] = (__bf16)fmaxf(ha[g*4+i], 0.f);
            int slab = (g >> 1) * 4 + wave;   // t = g>>1, mtile = wave
            *(bf16x4*)&hs[cb][slab][(g & 1) * 256 + l31 * 8 + hh * 4] = hv;
        }

        // barrier WITHOUT vmcnt drain: B loads stay in flight
        asm volatile("s_waitcnt lgkmcnt(0)\n\ts_barrier" ::: "memory");

        #pragma unroll
        for (int t = 0; t < 2; t++)
            #pragma unroll
            for (int mi = 0; mi < 2; mi++) {
                bf16x8 af = *(const bf16x8*)&hs[cb][t*4 + wr*2 + mi][hh * 256 + l31 * 8];
                #pragma unroll
                for (int ni = 0; ni < 4; ni++)
                    acc[mi][ni] = __builtin_amdgcn_mfma_f32_32x32x16_bf16(
                                      af, Bf[ni*2+t], acc[mi][ni], 0, 0, 0);
            }
    }

    // epilogue: C/D layout col=lane&31, row=(r&3)+8*(r>>2)+4*hh
    #pragma unroll
    for (int ni = 0; ni < 4; ni++) {
        int col = bn*BN + wc*128 + ni*32 + l31;
        float bias2 = b2[col];
        #pragma unroll
        for (int mi = 0; mi < 2; mi++) {
            int rbase = bm*BM + wr*64 + mi*32 + 4*hh;
            #pragma unroll
            for (int r = 0; r < 16; r++) {
                int rr = rbase + (r & 3) + 8 * (r >> 2);
                C[(size_t)rr * EMB + col] = acc[mi][ni][r] + bias2;
            }
        }
    }
}

extern "C" void kernel_launch(void* const* d_in, const int* in_sizes, int n_in,
                              void* d_out, int out_size, void* d_ws, size_t ws_size,
                              hipStream_t stream) {
    const float* x      = (const float*)d_in[0];  // [16,2048,8]
    const float* params = (const float*)d_in[1];  // [8,3]
    const float* W1     = (const float*)d_in[2];  // [2048,8]
    const float* b1     = (const float*)d_in[3];  // [2048]
    const float* W2     = (const float*)d_in[4];  // [512,2048]
    const float* b2     = (const float*)d_in[5];  // [512]
    float* out = (float*)d_out;                   // [32768,512]

    char* ws = (char*)d_ws;
    __hip_bfloat16* W2b = (__hip_bfloat16*)ws;                     // 2 MB
    __hip_bfloat16* W1b = (__hip_bfloat16*)(ws + 2097152);         // 32 KB
    __hip_bfloat16* b1b = (__hip_bfloat16*)(ws + 2097152 + 32768); // 4 KB

    k_prep<<<1025, 256, 0, stream>>>(W2, W1, b1, W2b, W1b, b1b);
    k_gemm<<<(NS/BM) * (EMB/BN), 256, 0, stream>>>(x, params, W1b, b1b, W2b, b2, out);
}